// Round 3
// baseline (114.741 us; speedup 1.0000x reference)
//
#include <hip/hip_runtime.h>

#define NN 256   // nodes per graph
#define DM 128   // gcn hidden dim
#define NH 4     // heads
#define LK 72    // row stride (elems) for ks/qs/RsT
#define LT 264   // row stride for vsT/Ps/Os
#define LX 136   // row stride for staged x

typedef __bf16 bf16;
typedef __attribute__((ext_vector_type(8))) __bf16 bf16x8;
typedef __attribute__((ext_vector_type(4))) float f32x4;
typedef __attribute__((ext_vector_type(16))) float f32x16;

static __device__ __forceinline__ unsigned short f2b(float f) {
  return __builtin_bit_cast(unsigned short, (__bf16)f);
}
static __device__ __forceinline__ bf16x8 ldf(const unsigned short* p) {
  return *(const bf16x8*)p;
}
static __device__ __forceinline__ void st4(unsigned short* p, float a, float b, float c, float d) {
  ushort4 v; v.x = f2b(a); v.y = f2b(b); v.z = f2b(c); v.w = f2b(d);
  *(ushort4*)p = v;   // single 8B LDS store
}

#define MFMA16(a,b,c) __builtin_amdgcn_mfma_f32_16x16x32_bf16((a),(b),(c),0,0,0)
#define MFMA32(a,b,c) __builtin_amdgcn_mfma_f32_32x32x16_bf16((a),(b),(c),0,0,0)
#define Z4  {0.f,0.f,0.f,0.f}
#define Z16 {0.f,0.f,0.f,0.f,0.f,0.f,0.f,0.f,0.f,0.f,0.f,0.f,0.f,0.f,0.f,0.f}

__global__ __launch_bounds__(512, 2)
void vlrgat_kernel(const float* __restrict__ gnn,
                   const float* __restrict__ Wq, const float* __restrict__ Wk,
                   const float* __restrict__ Wv, const float* __restrict__ Wfc,
                   const float* __restrict__ ln1g, const float* __restrict__ ln1b,
                   const float* __restrict__ ln2g, const float* __restrict__ ln2b,
                   float* __restrict__ out)
{
  __shared__ __align__(16) unsigned short ks [NN * LK];   // K  [m=256][d=64]
  __shared__ __align__(16) unsigned short qs [NN * LK];   // Q  [q=256][d=64] (pre-scaled)
  __shared__ __align__(16) unsigned short vsT[64 * LT];   // V^T [e=64][n=256]
  __shared__ __align__(16) unsigned short RsT[64 * LK];   // R^T [e=64][q=64]
  __shared__ __align__(16) unsigned short U  [128 * LX];  // x-stage [128][136] | Ps [64][264] | Os [64][264]
  __shared__ __align__(16) float2 smv[8][66];             // per-wave softmax partials

  unsigned short* const Ps = U;

  const int t   = threadIdx.x;
  const int w   = t >> 6;     // wave 0..7
  const int l   = t & 63;
  const int lr  = l & 15;     // 16x16 helpers
  const int lg  = l >> 4;
  const int l31 = l & 31;     // 32x32 helpers
  const int lh  = l >> 5;
  const int cb  = blockIdx.x;
  const float* const xg = gnn + (size_t)cb * NN * DM;

  f32x4 oacc[NH][2];
#pragma unroll
  for (int h = 0; h < NH; ++h) { oacc[h][0] = (f32x4)Z4; oacc[h][1] = (f32x4)Z4; }

  // stage 128 rows of x -> U bf16, fully coalesced (1KB/instr), packed b64 LDS writes
  auto stage_x = [&](int r0) {
#pragma unroll
    for (int k2 = 0; k2 < 8; ++k2) {
      const int idx = t + k2 * 512;
      const int row = idx >> 5;
      const int c4  = (idx & 31) * 4;
      float4 f = *(const float4*)(xg + (size_t)(r0 + row) * DM + c4);
      st4(&U[row * LX + c4], f.x, f.y, f.z, f.w);
    }
  };

  // 32x32 fragment gather from [128][256] fp32 weight: elem j -> W[(dbase+j)*256 + col]
  auto wf32 = [&](const float* __restrict__ W, int dbase, int col) -> bf16x8 {
    bf16x8 r;
#pragma unroll
    for (int j = 0; j < 8; ++j) r[j] = (bf16)W[(size_t)(dbase + j) * 256 + col];
    return r;
  };
  // 16x16 fragment gather (epilogue, Wfc [256][64])
  auto wf16 = [&](const float* __restrict__ W, int ld, int k0, int col) -> bf16x8 {
    bf16x8 r;
#pragma unroll
    for (int j = 0; j < 8; ++j) r[j] = (bf16)W[(size_t)(k0 + j) * ld + col];
    return r;
  };

#pragma unroll
  for (int h = 0; h < NH; ++h) {
    // ================= K/V/Q projection (32x32, packed writes) =================
#pragma unroll
    for (int half = 0; half < 2; ++half) {
      stage_x(half * 128);
      __syncthreads();                       // stage visible (also drains prior readers)
      bf16x8 xa[8];
      const int nl = (w & 3) * 32 + l31;     // local row in this half
#pragma unroll
      for (int c = 0; c < 8; ++c)
        xa[c] = ldf(&U[nl * LX + c * 16 + lh * 8]);
      const int n0 = half * 128 + (w & 3) * 32;
      if (w < 4) {
        // K^T = Wk^T x^T  -> row-major ks[n][e], packed writes
#pragma unroll
        for (int e = 0; e < 2; ++e) {
          f32x16 a = Z16;
#pragma unroll
          for (int c = 0; c < 8; ++c)
            a = MFMA32(wf32(Wk, c * 16 + lh * 8, h * 64 + e * 32 + l31), xa[c], a);
#pragma unroll
          for (int g2 = 0; g2 < 4; ++g2)
            st4(&ks[(n0 + l31) * LK + e * 32 + g2 * 8 + lh * 4],
                a[g2*4], a[g2*4+1], a[g2*4+2], a[g2*4+3]);
        }
        // Q^T (e-blk 0), pre-scaled by 1/8
        {
          f32x16 a = Z16;
#pragma unroll
          for (int c = 0; c < 8; ++c)
            a = MFMA32(wf32(Wq, c * 16 + lh * 8, h * 64 + l31), xa[c], a);
#pragma unroll
          for (int g2 = 0; g2 < 4; ++g2)
            st4(&qs[(n0 + l31) * LK + g2 * 8 + lh * 4],
                a[g2*4]*0.125f, a[g2*4+1]*0.125f, a[g2*4+2]*0.125f, a[g2*4+3]*0.125f);
        }
      } else {
        // V normal -> vsT[e][n], packed writes
#pragma unroll
        for (int e = 0; e < 2; ++e) {
          f32x16 a = Z16;
#pragma unroll
          for (int c = 0; c < 8; ++c)
            a = MFMA32(xa[c], wf32(Wv, c * 16 + lh * 8, h * 64 + e * 32 + l31), a);
#pragma unroll
          for (int g2 = 0; g2 < 4; ++g2)
            st4(&vsT[(e * 32 + l31) * LT + n0 + g2 * 8 + lh * 4],
                a[g2*4], a[g2*4+1], a[g2*4+2], a[g2*4+3]);
        }
        // Q^T (e-blk 1)
        {
          f32x16 a = Z16;
#pragma unroll
          for (int c = 0; c < 8; ++c)
            a = MFMA32(wf32(Wq, c * 16 + lh * 8, h * 64 + 32 + l31), xa[c], a);
#pragma unroll
          for (int g2 = 0; g2 < 4; ++g2)
            st4(&qs[(n0 + l31) * LK + 32 + g2 * 8 + lh * 4],
                a[g2*4]*0.125f, a[g2*4+1]*0.125f, a[g2*4+2]*0.125f, a[g2*4+3]*0.125f);
        }
      }
      __syncthreads();   // half0: before restage; half1: publish K/Q/V
    }

    // hoisted qb-invariant fragments
    bf16x8 ka[4];        // K rows m-blk w (for S)
#pragma unroll
    for (int c = 0; c < 4; ++c)
      ka[c] = ldf(&ks[(w * 32 + l31) * LK + c * 16 + lh * 8]);
    bf16x8 vb[2][8];     // V columns for PV (wave's 2 e-tiles)
#pragma unroll
    for (int et = 0; et < 2; ++et)
#pragma unroll
      for (int c = 0; c < 8; ++c)
        vb[et][c] = ldf(&vsT[(((w >> 2) * 2 + et) * 16 + lr) * LT + c * 32 + lg * 8]);

    // ================= attention: 4 tiles of 64 query rows =================
    for (int qb = 0; qb < 4; ++qb) {
      // S^T = K q^T : wave owns m-blk w (32 keys) x all 64 q
      f32x16 s0 = Z16, s1 = Z16;
#pragma unroll
      for (int c = 0; c < 4; ++c) {
        s0 = MFMA32(ka[c], ldf(&qs[(qb * 64 + l31) * LK + c * 16 + lh * 8]), s0);
        s1 = MFMA32(ka[c], ldf(&qs[(qb * 64 + 32 + l31) * LK + c * 16 + lh * 8]), s1);
      }
      // local stats over this wave's 32 keys (16 regs + lane^32 partner)
      float mw0 = s0[0], mw1 = s1[0];
#pragma unroll
      for (int i = 1; i < 16; ++i) { mw0 = fmaxf(mw0, s0[i]); mw1 = fmaxf(mw1, s1[i]); }
      mw0 = fmaxf(mw0, __shfl_xor(mw0, 32));
      mw1 = fmaxf(mw1, __shfl_xor(mw1, 32));
      float sw0 = 0.f, sw1 = 0.f;
#pragma unroll
      for (int i = 0; i < 16; ++i) {
        s0[i] = __expf(s0[i] - mw0); sw0 += s0[i];
        s1[i] = __expf(s1[i] - mw1); sw1 += s1[i];
      }
      sw0 += __shfl_xor(sw0, 32);
      sw1 += __shfl_xor(sw1, 32);
      if (l < 32) {
        smv[w][l31]      = make_float2(mw0, sw0);
        smv[w][32 + l31] = make_float2(mw1, sw1);
      }
      __syncthreads();                         // B1: stats ready
      float m80 = -3.4e38f, m81 = -3.4e38f;
      float2 t0[8], t1[8];
#pragma unroll
      for (int ww = 0; ww < 8; ++ww) {
        t0[ww] = smv[ww][l31];      m80 = fmaxf(m80, t0[ww].x);
        t1[ww] = smv[ww][32 + l31]; m81 = fmaxf(m81, t1[ww].x);
      }
      float S80 = 0.f, S81 = 0.f;
#pragma unroll
      for (int ww = 0; ww < 8; ++ww) {
        S80 += t0[ww].y * __expf(t0[ww].x - m80);
        S81 += t1[ww].y * __expf(t1[ww].x - m81);
      }
      const float fac0 = __expf(mw0 - m80) / S80;
      const float fac1 = __expf(mw1 - m81) / S81;
      // write normalized P (packed b64)
#pragma unroll
      for (int g2 = 0; g2 < 4; ++g2) {
        const int mo = w * 32 + g2 * 8 + lh * 4;
        st4(&Ps[l31 * LT + mo],
            s0[g2*4]*fac0, s0[g2*4+1]*fac0, s0[g2*4+2]*fac0, s0[g2*4+3]*fac0);
        st4(&Ps[(32 + l31) * LT + mo],
            s1[g2*4]*fac1, s1[g2*4+1]*fac1, s1[g2*4+2]*fac1, s1[g2*4+3]*fac1);
      }
      __syncthreads();                         // B2: P ready

      // R = P @ V (16x16): wave (q-blk w&3, e-half w>>2) -> RsT packed
      bf16x8 pa[8];
#pragma unroll
      for (int c = 0; c < 8; ++c)
        pa[c] = ldf(&Ps[((w & 3) * 16 + lr) * LT + c * 32 + lg * 8]);
#pragma unroll
      for (int et = 0; et < 2; ++et) {
        f32x4 ra = Z4;
#pragma unroll
        for (int c = 0; c < 8; ++c) ra = MFMA16(pa[c], vb[et][c], ra);
        st4(&RsT[(((w >> 2) * 2 + et) * 16 + lr) * LK + (w & 3) * 16 + lg * 4],
            ra[0], ra[1], ra[2], ra[3]);
      }
      __syncthreads();                         // B3: R ready

      // O += V_blk^T @ R : wave (d-blk w&3, e-half w>>2), accum in regs
      bf16x8 va[2];
#pragma unroll
      for (int c = 0; c < 2; ++c)
        va[c] = ldf(&vsT[((w & 3) * 16 + lr) * LT + qb * 64 + c * 32 + lg * 8]);
#pragma unroll
      for (int et = 0; et < 2; ++et)
#pragma unroll
        for (int c = 0; c < 2; ++c)
          oacc[h][et] = MFMA16(va[c],
              ldf(&RsT[(((w >> 2) * 2 + et) * 16 + lr) * LK + c * 32 + lg * 8]),
              oacc[h][et]);
    } // qb
  } // h

  // ================= epilogue: Os -> @Wfc -> LN -> LN =================
#pragma unroll
  for (int h2 = 0; h2 < NH; ++h2)
#pragma unroll
    for (int et = 0; et < 2; ++et)
#pragma unroll
      for (int r = 0; r < 4; ++r)
        U[((w & 3) * 16 + lg * 4 + r) * LT + h2 * 64 + ((w >> 2) * 2 + et) * 16 + lr] =
            f2b(oacc[h2][et][r]);
  __syncthreads();

  if (w < 4) {
    bf16x8 oa[8];
#pragma unroll
    for (int kt = 0; kt < 8; ++kt)
      oa[kt] = ldf(&U[(w * 16 + lr) * LT + kt * 32 + lg * 8]);
    f32x4 fa[4];
#pragma unroll
    for (int ct = 0; ct < 4; ++ct) {
      f32x4 a = Z4;
#pragma unroll
      for (int kt = 0; kt < 8; ++kt)
        a = MFMA16(oa[kt], wf16(Wfc, 64, kt * 32 + lg * 8, ct * 16 + lr), a);
      fa[ct] = a;
    }

    float g1v[4], b1v[4], g2v[4], b2v[4];
#pragma unroll
    for (int ct = 0; ct < 4; ++ct) {
      g1v[ct] = ln1g[ct * 16 + lr];
      b1v[ct] = ln1b[ct * 16 + lr];
      g2v[ct] = ln2g[ct * 16 + lr];
      b2v[ct] = ln2b[ct * 16 + lr];
    }
    const int bb = cb & 31;
    const int ch = cb >> 5;
    float* const obase = out + (size_t)(bb * 8 + ch) * 64 * 64;
#pragma unroll
    for (int r = 0; r < 4; ++r) {
      const int row = w * 16 + lg * 4 + r;
      float x0 = fa[0][r], x1 = fa[1][r], x2 = fa[2][r], x3 = fa[3][r];
      float mu = x0 + x1 + x2 + x3;
      mu += __shfl_xor(mu, 1); mu += __shfl_xor(mu, 2);
      mu += __shfl_xor(mu, 4); mu += __shfl_xor(mu, 8);
      mu *= 0.015625f;
      float d0 = x0 - mu, d1 = x1 - mu, d2 = x2 - mu, d3 = x3 - mu;
      float vr = d0*d0 + d1*d1 + d2*d2 + d3*d3;
      vr += __shfl_xor(vr, 1); vr += __shfl_xor(vr, 2);
      vr += __shfl_xor(vr, 4); vr += __shfl_xor(vr, 8);
      const float is1 = rsqrtf(vr * 0.015625f + 1e-6f);
      float y0 = d0*is1*g1v[0] + b1v[0];
      float y1 = d1*is1*g1v[1] + b1v[1];
      float y2 = d2*is1*g1v[2] + b1v[2];
      float y3 = d3*is1*g1v[3] + b1v[3];
      float mu2 = y0 + y1 + y2 + y3;
      mu2 += __shfl_xor(mu2, 1); mu2 += __shfl_xor(mu2, 2);
      mu2 += __shfl_xor(mu2, 4); mu2 += __shfl_xor(mu2, 8);
      mu2 *= 0.015625f;
      float e0 = y0-mu2, e1 = y1-mu2, e2 = y2-mu2, e3 = y3-mu2;
      float v2 = e0*e0 + e1*e1 + e2*e2 + e3*e3;
      v2 += __shfl_xor(v2, 1); v2 += __shfl_xor(v2, 2);
      v2 += __shfl_xor(v2, 4); v2 += __shfl_xor(v2, 8);
      const float is2 = rsqrtf(v2 * 0.015625f + 1e-6f);
      float* const op = obase + (size_t)row * 64;
      op[ 0 + lr] = e0*is2*g2v[0] + b2v[0];
      op[16 + lr] = e1*is2*g2v[1] + b2v[1];
      op[32 + lr] = e2*is2*g2v[2] + b2v[2];
      op[48 + lr] = e3*is2*g2v[3] + b2v[3];
    }
  }
}

extern "C" void kernel_launch(void* const* d_in, const int* in_sizes, int n_in,
                              void* d_out, int out_size, void* d_ws, size_t ws_size,
                              hipStream_t stream) {
  const float* gnn = (const float*)d_in[0];
  const float* Wq  = (const float*)d_in[1];
  const float* Wk  = (const float*)d_in[2];
  const float* Wv  = (const float*)d_in[3];
  const float* Wfc = (const float*)d_in[4];
  const float* l1g = (const float*)d_in[5];
  const float* l1b = (const float*)d_in[6];
  const float* l2g = (const float*)d_in[7];
  const float* l2b = (const float*)d_in[8];
  (void)in_sizes; (void)n_in; (void)d_ws; (void)ws_size; (void)out_size;
  vlrgat_kernel<<<dim3(256), dim3(512), 0, stream>>>(
      gnn, Wq, Wk, Wv, Wfc, l1g, l1b, l2g, l2b, (float*)d_out);
}